// Round 20
// baseline (114.227 us; speedup 1.0000x reference)
//
#include <hip/hip_runtime.h>
#include <hip/hip_bf16.h>
#include <math.h>

#define N_ROWS  100000
#define NT_ROW  6250            // 16-row tiles, exact: 6250*16 = 100000

typedef __attribute__((ext_vector_type(8))) short bf16x8;   // 4 VGPR A/B frag
typedef __attribute__((ext_vector_type(4))) float f32x4;    // C/D frag

__device__ __forceinline__ float silu_f(float v) {
    return v * (1.0f / (1.0f + __expf(-v)));
}
__device__ __forceinline__ short f2bf(float f) {
    union { __hip_bfloat16 h; short s; } u;
    u.h = __float2bfloat16(f);          // RNE convert
    return u.s;
}
// async global->LDS, NON-TEMPORAL (aux=2): x is a zero-reuse stream (r17 win)
__device__ __forceinline__ void stage16nt(const float* g, float* l) {
    __builtin_amdgcn_global_load_lds(
        (const __attribute__((address_space(1))) unsigned int*)g,
        (__attribute__((address_space(3))) unsigned int*)l,
        16, 0, 2);
}

// ---- pre-kernel: fragment-packed weights (unchanged, verified) -------------
// wTf[(t*8+p)*1024 B + lane*16 B] = B-fragment for col-tile t, K-pass p.
__global__ __launch_bounds__(64)
void prep_wT(const float* __restrict__ w1_s, const float* __restrict__ w1_v,
             unsigned short* __restrict__ wTf)
{
    const int tp = blockIdx.x;               // 0..159 = t*8 + p
    const int t = tp >> 3, p = tp & 7;
    const int lane = threadIdx.x;            // 0..63
    const int l15 = lane & 15, lq = lane >> 4;
    const float* src  = (t < 8) ? w1_s : w1_v;
    const int    strd = (t < 8) ? 128 : 64;
    const int    scol = (t < 8) ? (t * 16 + l15) : (((t - 8) & 3) * 16 + l15);
    const int    k0   = 32 * p + 8 * lq;
    unsigned short o[8];
    #pragma unroll
    for (int e = 0; e < 8; ++e)
        o[e] = (unsigned short)f2bf(src[(k0 + e) * strd + scol]);
    *(ushort4*)(wTf + (size_t)tp * 512 + lane * 8)     = make_ushort4(o[0], o[1], o[2], o[3]);
    *(ushort4*)(wTf + (size_t)tp * 512 + lane * 8 + 4) = make_ushort4(o[4], o[5], o[6], o[7]);
}

// ---- main: 1 block = 1 16-row tile, staged WHOLE and CONTIGUOUS ------------
// DRAM-page fix: each 4KB x-row is read once, contiguously (vs 8 separated
// 512B windows in r17). Swizzle: LDS granule (row, G) holds global granule
// G ^ (row&7) — XOR within 128B windows, so global reads stay contiguous and
// the r13-verified read indexing applies. One vmcnt(0)+barrier per block
// lifetime; stage/compute overlap comes from 2 blocks/CU anti-phase.
// Wave w stages rows 4w..4w+3 and computes col-tiles {w,4+w,8+w,12+w,16+w}.
__global__ __launch_bounds__(256, 2)
void ndr_mfma_kernel(const float* __restrict__ x,
                     const unsigned short* __restrict__ wTf,
                     const float* __restrict__ w2_s,
                     const float* __restrict__ w2_v,
                     float* __restrict__ out)
{
    __shared__ float  tile[16][1024];        // 64 KB: whole tile, f32
    __shared__ float4 red[4][16];            // 1 KB cross-wave partials

    const int lane = threadIdx.x & 63;
    const int wid  = threadIdx.x >> 6;       // wave 0..3
    const int l15  = lane & 15, lq = lane >> 4, r7 = l15 & 7;
    const long long n0 = (long long)blockIdx.x * 16;

    const float w2sv = w2_s[16 * wid + l15];
    const float w2vv = w2_v[16 * wid + l15];

    // ---- stage: rows 4wid..4wid+3, each as 4 contiguous 1KB instrs ----
    #pragma unroll
    for (int rr = 0; rr < 4; ++rr) {
        const int row = 4 * wid + rr;
        const float* rbase = x + (n0 + row) * 1024;
        const int lx = (lane ^ (row & 7)) * 4;   // inverse swizzle, in-window
        #pragma unroll
        for (int q = 0; q < 4; ++q)
            stage16nt(rbase + q * 256 + lx, &tile[row][q * 256]);
    }
    asm volatile("s_waitcnt vmcnt(0)" ::: "memory");
    __builtin_amdgcn_s_barrier();

    f32x4 acc[5];
    #pragma unroll
    for (int t = 0; t < 5; ++t) acc[t] = (f32x4){0.f, 0.f, 0.f, 0.f};

    const char*  wbase = (const char*)wTf + lane * 16;
    const float* rb    = &tile[l15][0];      // my A-row

    #pragma unroll 1
    for (int p = 0; p < 8; ++p) {
        // B fragments for this wave's 5 tiles (L1/L2-resident, coalesced 1KB)
        bf16x8 bf[5];
        #pragma unroll
        for (int u = 0; u < 5; ++u)
            bf[u] = *(const bf16x8*)(wbase + (size_t)(wid + 4 * u) * 8192
                                           + (size_t)p * 1024);

        // A from LDS (r13-verified granule indexing, swizzle ^r7)
        f32x4 s0 = *(const f32x4*)(rb + 4 * ((8 * p + 2 * lq    ) ^ r7));
        f32x4 s1 = *(const f32x4*)(rb + 4 * ((8 * p + 2 * lq + 1) ^ r7));
        f32x4 v0 = *(const f32x4*)(rb + 4 * ((64 + 24 * p + 6 * lq + 0) ^ r7));
        f32x4 v1 = *(const f32x4*)(rb + 4 * ((64 + 24 * p + 6 * lq + 1) ^ r7));
        f32x4 v2 = *(const f32x4*)(rb + 4 * ((64 + 24 * p + 6 * lq + 2) ^ r7));
        f32x4 v3 = *(const f32x4*)(rb + 4 * ((64 + 24 * p + 6 * lq + 3) ^ r7));
        f32x4 v4 = *(const f32x4*)(rb + 4 * ((64 + 24 * p + 6 * lq + 4) ^ r7));
        f32x4 v5 = *(const f32x4*)(rb + 4 * ((64 + 24 * p + 6 * lq + 5) ^ r7));

        const float xs[8]  = {s0.x, s0.y, s0.z, s0.w, s1.x, s1.y, s1.z, s1.w};
        const float xv[24] = {v0.x, v0.y, v0.z, v0.w, v1.x, v1.y, v1.z, v1.w,
                              v2.x, v2.y, v2.z, v2.w, v3.x, v3.y, v3.z, v3.w,
                              v4.x, v4.y, v4.z, v4.w, v5.x, v5.y, v5.z, v5.w};
        bf16x8 a_s, a_v0, a_v1, a_v2;        // A[row=l15][k=32p+8lq+e]
        #pragma unroll
        for (int e = 0; e < 8; ++e) {
            a_s[e]  = f2bf(xs[e]);
            a_v0[e] = f2bf(xv[3 * e + 0]);
            a_v1[e] = f2bf(xv[3 * e + 1]);
            a_v2[e] = f2bf(xv[3 * e + 2]);
        }

        acc[0] = __builtin_amdgcn_mfma_f32_16x16x32_bf16(a_s,  bf[0], acc[0], 0, 0, 0);
        acc[1] = __builtin_amdgcn_mfma_f32_16x16x32_bf16(a_s,  bf[1], acc[1], 0, 0, 0);
        acc[2] = __builtin_amdgcn_mfma_f32_16x16x32_bf16(a_v0, bf[2], acc[2], 0, 0, 0);
        acc[3] = __builtin_amdgcn_mfma_f32_16x16x32_bf16(a_v1, bf[3], acc[3], 0, 0, 0);
        acc[4] = __builtin_amdgcn_mfma_f32_16x16x32_bf16(a_v2, bf[4], acc[4], 0, 0, 0);
    }

    // ---- epilogue: silu-gate + layer 2 (r12-verified) ----------------------
    const float inv_in = 0.0625f, inv_h = 0.125f;
    #pragma unroll
    for (int j = 0; j < 4; ++j) {
        float hs = acc[0][j] * inv_in;       // scalars col 16wid+l15
        float hg = acc[1][j] * inv_in;       // gates   col 16wid+l15
        float gg = silu_f(hg);
        float ps  = silu_f(hs) * w2sv;
        float pv0 = gg * (acc[2][j] * inv_in) * w2vv;
        float pv1 = gg * (acc[3][j] * inv_in) * w2vv;
        float pv2 = gg * (acc[4][j] * inv_in) * w2vv;
        #pragma unroll
        for (int off = 1; off <= 8; off <<= 1) {   // reduce over 16 l15 lanes
            ps  += __shfl_xor(ps,  off, 64);
            pv0 += __shfl_xor(pv0, off, 64);
            pv1 += __shfl_xor(pv1, off, 64);
            pv2 += __shfl_xor(pv2, off, 64);
        }
        if (l15 == 0)
            red[wid][lq * 4 + j] = make_float4(ps, pv0, pv1, pv2);
    }
    __syncthreads();
    if (wid == 0 && lane < 16) {             // lane = row within tile
        float4 a = red[0][lane], b = red[1][lane],
               c = red[2][lane], d = red[3][lane];
        *(float4*)(out + (n0 + lane) * 4) =
            make_float4((a.x + b.x + c.x + d.x) * inv_h,
                        (a.y + b.y + c.y + d.y) * inv_h,
                        (a.z + b.z + c.z + d.z) * inv_h,
                        (a.w + b.w + c.w + d.w) * inv_h);
    }
}

extern "C" void kernel_launch(void* const* d_in, const int* in_sizes, int n_in,
                              void* d_out, int out_size, void* d_ws, size_t ws_size,
                              hipStream_t stream) {
    const float* x    = (const float*)d_in[0];
    const float* w1_s = (const float*)d_in[1];
    const float* w1_v = (const float*)d_in[2];
    const float* w2_s = (const float*)d_in[3];
    const float* w2_v = (const float*)d_in[4];
    float* out = (float*)d_out;
    unsigned short* wTf = (unsigned short*)d_ws;      // 160*512*2 = 160 KB

    prep_wT<<<160, 64, 0, stream>>>(w1_s, w1_v, wTf);
    ndr_mfma_kernel<<<NT_ROW, 256, 0, stream>>>(x, wTf, w2_s, w2_v, out);
}

// Round 21
// 94.091 us; speedup vs baseline: 1.2140x; 1.2140x over previous
//
#include <hip/hip_runtime.h>
#include <hip/hip_bf16.h>
#include <math.h>

#define N_ROWS  100000
#define NT_ROW  6250            // 16-row MFMA tiles, exact

typedef __attribute__((ext_vector_type(8))) short bf16x8;   // 4 VGPR A/B frag
typedef __attribute__((ext_vector_type(4))) float f32x4;    // C/D frag

__device__ __forceinline__ float silu_f(float v) {
    return v * (1.0f / (1.0f + __expf(-v)));
}
__device__ __forceinline__ short f2bf(float f) {
    union { __hip_bfloat16 h; short s; } u;
    u.h = __float2bfloat16(f);          // RNE convert
    return u.s;
}
// async global->LDS with NON-TEMPORAL policy (aux=2): x is a zero-reuse
// stream; no-allocate keeps L2 for the B weights (r17-verified win).
__device__ __forceinline__ void stage16nt(const float* g, float* l) {
    __builtin_amdgcn_global_load_lds(
        (const __attribute__((address_space(1))) unsigned int*)g,
        (__attribute__((address_space(3))) unsigned int*)l,
        16, 0, 2);
}

// ---- pre-kernel: fragment-packed weights (unchanged, verified) -------------
// wTf[(t*8+p)*1024 B + lane*16 B] = B-fragment for col-tile t, K-pass p.
// Only tiles 0..11 are READ by the main kernel now (12..19 duplicate 8..11),
// but writing all 20 keeps this kernel byte-identical to the verified one.
__global__ __launch_bounds__(64)
void prep_wT(const float* __restrict__ w1_s, const float* __restrict__ w1_v,
             unsigned short* __restrict__ wTf)
{
    const int tp = blockIdx.x;               // 0..159 = t*8 + p
    const int t = tp >> 3, p = tp & 7;
    const int lane = threadIdx.x;            // 0..63
    const int l15 = lane & 15, lq = lane >> 4;
    const float* src  = (t < 8) ? w1_s : w1_v;
    const int    strd = (t < 8) ? 128 : 64;
    const int    scol = (t < 8) ? (t * 16 + l15) : (((t - 8) & 3) * 16 + l15);
    const int    k0   = 32 * p + 8 * lq;
    unsigned short o[8];
    #pragma unroll
    for (int e = 0; e < 8; ++e)
        o[e] = (unsigned short)f2bf(src[(k0 + e) * strd + scol]);
    *(ushort4*)(wTf + (size_t)tp * 512 + lane * 8)     = make_ushort4(o[0], o[1], o[2], o[3]);
    *(ushort4*)(wTf + (size_t)tp * 512 + lane * 8 + 4) = make_ushort4(o[4], o[5], o[6], o[7]);
}

// ---- main kernel: r17 champion + B-fragment DEDUP --------------------------
// Tiles 8-11, 12-15, 16-19 share identical w1_v B-fragments; load the 4
// distinct v-fragments once and feed them to a_v0/a_v1/a_v2's MFMAs.
// B loads/pass: 20 -> 12 (L2 traffic 1.0 GB -> 0.6 GB), numerics unchanged.
__global__ __launch_bounds__(256, 2)
void ndr_mfma_kernel(const float* __restrict__ x,
                     const unsigned short* __restrict__ wTf,
                     const float* __restrict__ w2_s,
                     const float* __restrict__ w2_v,
                     float* __restrict__ out)
{
    __shared__ float lds[2][4][2048];        // [buf][wave][16*128 floats] = 64 KB

    const int lane = threadIdx.x & 63;
    const int wid  = threadIdx.x >> 6;
    const int rt   = blockIdx.x * 4 + wid;
    if (rt >= NT_ROW) return;                // no barriers anywhere -> safe
    const int l15 = lane & 15, lq = lane >> 4;
    const long long n0 = (long long)rt * 16;

    // --- staging map (constant across passes) ---
    // chunk j covers rows 2j (lanes 0-31), 2j+1 (lanes 32-63); slot = lane&31.
    const int sub = lane >> 5, slot = lane & 31;
    const float* sp[8];                      // per-lane global src for pass 0
    int sstep[8];                            // float advance per pass
    #pragma unroll
    for (int j = 0; j < 8; ++j) {
        const int row = 2 * j + sub;
        const int g   = slot ^ (row & 7);    // inverse-swizzled source segment
        const int isxs = (g < 8);
        const int f0  = isxs ? 4 * g : 256 + 4 * (g - 8);
        sstep[j] = isxs ? 32 : 96;
        sp[j] = x + (n0 + row) * 1024 + f0;
    }

    f32x4 acc[20];
    #pragma unroll
    for (int t = 0; t < 20; ++t) acc[t] = (f32x4){0.f, 0.f, 0.f, 0.f};

    const char* wbase = (const char*)wTf + lane * 16;

    // --- prologue: stage pass 0 -> buf0, pass 1 -> buf1 ---
    #pragma unroll
    for (int j = 0; j < 8; ++j) stage16nt(sp[j],            &lds[0][wid][j * 256]);
    #pragma unroll
    for (int j = 0; j < 8; ++j) stage16nt(sp[j] + sstep[j], &lds[1][wid][j * 256]);

    const int r7 = l15 & 7;
    const float* rb0 = &lds[0][wid][l15 * 128];
    const float* rb1 = &lds[1][wid][l15 * 128];

    #pragma unroll 1
    for (int p = 0; p < 8; ++p) {
        // buf[p&1] ready when everything older than the newest 8 stages landed
        if (p < 7) asm volatile("s_waitcnt vmcnt(8)" ::: "memory");
        else       asm volatile("s_waitcnt vmcnt(0)" ::: "memory");

        const float* rb = (p & 1) ? rb1 : rb0;
        // xs: segs 2lq, 2lq+1 ; xv: segs 8+6lq..8+6lq+5 (slot = seg ^ r7)
        f32x4 s0 = *(const f32x4*)(rb + 4 * (( 2 * lq     ) ^ r7));
        f32x4 s1 = *(const f32x4*)(rb + 4 * (( 2 * lq + 1 ) ^ r7));
        f32x4 v0 = *(const f32x4*)(rb + 4 * ((8 + 6 * lq + 0) ^ r7));
        f32x4 v1 = *(const f32x4*)(rb + 4 * ((8 + 6 * lq + 1) ^ r7));
        f32x4 v2 = *(const f32x4*)(rb + 4 * ((8 + 6 * lq + 2) ^ r7));
        f32x4 v3 = *(const f32x4*)(rb + 4 * ((8 + 6 * lq + 3) ^ r7));
        f32x4 v4 = *(const f32x4*)(rb + 4 * ((8 + 6 * lq + 4) ^ r7));
        f32x4 v5 = *(const f32x4*)(rb + 4 * ((8 + 6 * lq + 5) ^ r7));

        const float xs[8]  = {s0.x, s0.y, s0.z, s0.w, s1.x, s1.y, s1.z, s1.w};
        const float xv[24] = {v0.x, v0.y, v0.z, v0.w, v1.x, v1.y, v1.z, v1.w,
                              v2.x, v2.y, v2.z, v2.w, v3.x, v3.y, v3.z, v3.w,
                              v4.x, v4.y, v4.z, v4.w, v5.x, v5.y, v5.z, v5.w};
        bf16x8 a_s, a_v0, a_v1, a_v2;        // A[row=l15][k=32p+8lq+e]
        #pragma unroll
        for (int e = 0; e < 8; ++e) {
            a_s[e]  = f2bf(xs[e]);
            a_v0[e] = f2bf(xv[3 * e + 0]);
            a_v1[e] = f2bf(xv[3 * e + 1]);
            a_v2[e] = f2bf(xv[3 * e + 2]);
        }

        // B loads BEFORE the stage issue (in-flight stages stay newest).
        // DEDUP: 8 s-fragments + 4 distinct v-fragments (tiles 8-11).
        bf16x8 bfs[8], bfv[4];
        #pragma unroll
        for (int t = 0; t < 8; ++t)
            bfs[t] = *(const bf16x8*)(wbase + (size_t)p * 1024 + (size_t)t * 8192);
        #pragma unroll
        for (int u = 0; u < 4; ++u)
            bfv[u] = *(const bf16x8*)(wbase + (size_t)p * 1024 + (size_t)(8 + u) * 8192);

        // overwrite the just-consumed buffer with pass p+2 (LDS reads fenced)
        if (p + 2 < 8) {
            asm volatile("s_waitcnt lgkmcnt(0)" ::: "memory");
            #pragma unroll
            for (int j = 0; j < 8; ++j)
                stage16nt(sp[j] + (p + 2) * sstep[j], &lds[p & 1][wid][j * 256]);
        }

        #pragma unroll
        for (int t = 0; t < 8; ++t)
            acc[t] = __builtin_amdgcn_mfma_f32_16x16x32_bf16(a_s, bfs[t], acc[t], 0, 0, 0);
        #pragma unroll
        for (int u = 0; u < 4; ++u) {
            acc[8  + u] = __builtin_amdgcn_mfma_f32_16x16x32_bf16(a_v0, bfv[u], acc[8  + u], 0, 0, 0);
            acc[12 + u] = __builtin_amdgcn_mfma_f32_16x16x32_bf16(a_v1, bfv[u], acc[12 + u], 0, 0, 0);
            acc[16 + u] = __builtin_amdgcn_mfma_f32_16x16x32_bf16(a_v2, bfv[u], acc[16 + u], 0, 0, 0);
        }
    }

    // ---- epilogue: silu-gate + layer 2 in fp32 (unchanged, verified) -------
    const float inv_in = 0.0625f, inv_h = 0.125f;
    float w2sv[4], w2vv[4];
    #pragma unroll
    for (int u = 0; u < 4; ++u) {
        w2sv[u] = w2_s[u * 16 + l15];
        w2vv[u] = w2_v[u * 16 + l15];
    }
    #pragma unroll
    for (int j = 0; j < 4; ++j) {
        float ps = 0.f, pv0 = 0.f, pv1 = 0.f, pv2 = 0.f;
        #pragma unroll
        for (int u = 0; u < 4; ++u) {
            float hs = acc[u][j]     * inv_in;
            float hg = acc[4 + u][j] * inv_in;
            float gg = silu_f(hg);
            ps  += silu_f(hs) * w2sv[u];
            pv0 += gg * (acc[8  + u][j] * inv_in) * w2vv[u];
            pv1 += gg * (acc[12 + u][j] * inv_in) * w2vv[u];
            pv2 += gg * (acc[16 + u][j] * inv_in) * w2vv[u];
        }
        #pragma unroll
        for (int off = 1; off <= 8; off <<= 1) {
            ps  += __shfl_xor(ps,  off, 64);
            pv0 += __shfl_xor(pv0, off, 64);
            pv1 += __shfl_xor(pv1, off, 64);
            pv2 += __shfl_xor(pv2, off, 64);
        }
        if (l15 == 0) {
            long long n = n0 + lq * 4 + j;
            *(float4*)(out + n * 4) =
                make_float4(ps * inv_h, pv0 * inv_h, pv1 * inv_h, pv2 * inv_h);
        }
    }
}

extern "C" void kernel_launch(void* const* d_in, const int* in_sizes, int n_in,
                              void* d_out, int out_size, void* d_ws, size_t ws_size,
                              hipStream_t stream) {
    const float* x    = (const float*)d_in[0];
    const float* w1_s = (const float*)d_in[1];
    const float* w1_v = (const float*)d_in[2];
    const float* w2_s = (const float*)d_in[3];
    const float* w2_v = (const float*)d_in[4];
    float* out = (float*)d_out;
    unsigned short* wTf = (unsigned short*)d_ws;      // 160*512*2 = 160 KB

    prep_wT<<<160, 64, 0, stream>>>(w1_s, w1_v, wTf);
    int blocks = (NT_ROW + 3) / 4;                    // 1563; tail waves exit
    ndr_mfma_kernel<<<blocks, 256, 0, stream>>>(x, wTf, w2_s, w2_v, out);
}